// Round 1
// baseline (81.240 us; speedup 1.0000x reference)
//
#include <hip/hip_runtime.h>

// Problem constants (from reference): N=32, CIN=64, COUT=128, K=4, H=W=64
#define Nn   32
#define CIN  64
#define COUT 128
#define HWVOL 4096              // H*W
#define OHW_INV (1.0f/4489.0f)  // 1/((H+K-1)*(W+K-1)) = 1/67^2

// ---------------------------------------------------------------------------
// Stage 1: Sx[g] = sum over the 4096-element spatial plane g=(n*CIN+ci).
// One block (256 threads) per plane; each thread loads 4x float4 (coalesced),
// wave64 shuffle reduce, 4-partial LDS combine.
// ---------------------------------------------------------------------------
__global__ __launch_bounds__(256) void sum_x_kernel(const float* __restrict__ x,
                                                    float* __restrict__ Sx) {
    const int g = blockIdx.x;
    const int t = threadIdx.x;
    const float4* xp = (const float4*)(x + (size_t)g * HWVOL);
    float acc = 0.0f;
#pragma unroll
    for (int j = 0; j < 4; ++j) {
        float4 v = xp[t + 256 * j];
        acc += (v.x + v.y) + (v.z + v.w);
    }
    // wave (64-lane) reduce
#pragma unroll
    for (int off = 32; off > 0; off >>= 1)
        acc += __shfl_down(acc, off, 64);
    __shared__ float part[4];
    if ((t & 63) == 0) part[t >> 6] = acc;
    __syncthreads();
    if (t == 0) Sx[g] = (part[0] + part[1]) + (part[2] + part[3]);
}

// ---------------------------------------------------------------------------
// Stage 2: Sw[ci*COUT+co] = sum of the 16 contiguous kernel taps of weight
// (layout (CIN,COUT,K,K) -> flat (ci*COUT+co)*16 + k). 8192 outputs.
// ---------------------------------------------------------------------------
__global__ __launch_bounds__(256) void sum_w_kernel(const float* __restrict__ w,
                                                    float* __restrict__ Sw) {
    const int o = blockIdx.x * 256 + threadIdx.x;   // < CIN*COUT = 8192
    const float4* wp = (const float4*)(w + (size_t)o * 16);
    float4 a = wp[0], b = wp[1], c = wp[2], d = wp[3];
    Sw[o] = (((a.x + a.y) + (a.z + a.w)) + ((b.x + b.y) + (b.z + b.w))) +
            (((c.x + c.y) + (c.z + c.w)) + ((d.x + d.y) + (d.z + d.w)));
}

// ---------------------------------------------------------------------------
// Stage 3: per image n (one block, 128 threads = one per co):
//   pooled[co] = (sum_ci Sx[n,ci]*Sw[ci,co]) / 4489 + conv_bias[co] + extra_bias[co]
//   out[n]    = 10 * logsumexp_co(pooled)
// Sw reads are coalesced (stride COUT across lanes).
// ---------------------------------------------------------------------------
__global__ __launch_bounds__(128) void final_kernel(const float* __restrict__ Sx,
                                                    const float* __restrict__ Sw,
                                                    const float* __restrict__ conv_bias,
                                                    const float* __restrict__ extra_bias,
                                                    float* __restrict__ out) {
    const int n  = blockIdx.x;
    const int co = threadIdx.x;
    __shared__ float sxs[CIN];
    if (co < CIN) sxs[co] = Sx[n * CIN + co];
    __syncthreads();

    float acc = 0.0f;
#pragma unroll
    for (int ci = 0; ci < CIN; ++ci)
        acc = fmaf(sxs[ci], Sw[ci * COUT + co], acc);

    const float pooled = acc * OHW_INV + conv_bias[co] + extra_bias[co];

    __shared__ float red[COUT];
    red[co] = pooled;
    __syncthreads();
#pragma unroll
    for (int s = 64; s > 0; s >>= 1) {
        if (co < s) red[co] = fmaxf(red[co], red[co + s]);
        __syncthreads();
    }
    const float m = red[0];
    __syncthreads();
    red[co] = expf(pooled - m);
    __syncthreads();
#pragma unroll
    for (int s = 64; s > 0; s >>= 1) {
        if (co < s) red[co] += red[co + s];
        __syncthreads();
    }
    if (co == 0) out[n] = 10.0f * (m + logf(red[0]));
}

extern "C" void kernel_launch(void* const* d_in, const int* in_sizes, int n_in,
                              void* d_out, int out_size, void* d_ws, size_t ws_size,
                              hipStream_t stream) {
    const float* x          = (const float*)d_in[0];  // (32,64,64,64)
    const float* weight     = (const float*)d_in[1];  // (64,128,4,4)
    const float* conv_bias  = (const float*)d_in[2];  // (128,)
    const float* extra_bias = (const float*)d_in[3];  // (128,)
    float* out = (float*)d_out;                       // (32,1) fp32

    float* Sx = (float*)d_ws;          // 2048 floats
    float* Sw = Sx + Nn * CIN;         // 8192 floats

    sum_x_kernel<<<Nn * CIN, 256, 0, stream>>>(x, Sx);
    sum_w_kernel<<<(CIN * COUT) / 256, 256, 0, stream>>>(weight, Sw);
    final_kernel<<<Nn, 128, 0, stream>>>(Sx, Sw, conv_bias, extra_bias, out);
}